// Round 1
// baseline (824.245 us; speedup 1.0000x reference)
//
#include <hip/hip_runtime.h>
#include <hip/hip_bf16.h>
#include <stdint.h>

// Cross-attention: out = softmax((X Wq)(C Wk)^T / sqrt(D)) (C Wv) Wo
// Outputs: [B,S,D] fp32 output, then [B,S,S] fp32 softmax weights, concat in d_out.
// Strategy: bf16 MFMA GEMMs (m97 structure: 128x128 tile, BK=32, 16x16x32 mfma,
// global_load_lds width=16), fp32 accumulate. Scores land directly in d_out's
// weights region, softmax in-place + bf16 copy for the PV GEMM.

typedef __bf16 bf16;
typedef __attribute__((ext_vector_type(8))) __bf16 bf16x8;
typedef __attribute__((ext_vector_type(4))) float f32x4;

#define BM 128
#define BN 128
#define BK 32

__device__ __forceinline__ void g2lds16(const void* g, void* l) {
    __builtin_amdgcn_global_load_lds(
        (__attribute__((address_space(1))) void*)g,
        (__attribute__((address_space(3))) void*)l,
        16, 0, 0);
}

// C[m][n] = scale * sum_k A[m][k] * Bt[n][k]; A:[M,K] lda, Bt:[N,K] ldb, C:[M,N] ldc.
// M%128==0, N%128==0, K%32==0. blockIdx.z batches via strides sA/sB/sC (elements).
template <bool BF16OUT>
__global__ __launch_bounds__(256) void gemm_bt(
    const bf16* __restrict__ A, const bf16* __restrict__ Bt, void* __restrict__ Cv,
    int M, int N, int K, int lda, int ldb, int ldc,
    long sA, long sB, long sC, float scale)
{
    __shared__ bf16 As[BM * BK];
    __shared__ bf16 Bs[BN * BK];

    const int z = blockIdx.z;
    A  += (long)z * sA;
    Bt += (long)z * sB;

    const int t    = threadIdx.x;
    const int wave = t >> 6, lane = t & 63;
    const int wr   = wave >> 1, wc = wave & 1;   // 2x2 wave grid, 64x64 each
    const int lm   = lane & 15, lk = lane >> 4;  // mfma fragment coords

    const long by = (long)blockIdx.y * BM;
    const long bx = (long)blockIdx.x * BN;

    f32x4 acc[4][4] = {};

    // staging: thread t loads 16B; lane-contiguous LDS (global_load_lds constraint)
    const int srow = t >> 2;            // 0..63
    const int scol = (t & 3) * 8;       // 0,8,16,24
    const bf16* Ap = A  + (by + srow) * (long)lda + scol;
    const bf16* Bp = Bt + (bx + srow) * (long)ldb + scol;
    bf16* AsW = &As[t * 8];
    bf16* BsW = &Bs[t * 8];
    const long a64 = 64L * lda, b64 = 64L * ldb;

    for (int kt = 0; kt < K; kt += BK) {
        g2lds16(Ap,       AsW);
        g2lds16(Ap + a64, AsW + 64 * BK);
        g2lds16(Bp,       BsW);
        g2lds16(Bp + b64, BsW + 64 * BK);
        Ap += BK; Bp += BK;
        __builtin_amdgcn_s_waitcnt(0x0f70);   // vmcnt(0)
        __syncthreads();

        bf16x8 af[4], bfr[4];
        #pragma unroll
        for (int i = 0; i < 4; ++i)
            af[i] = *(const bf16x8*)&As[(wr * 64 + i * 16 + lm) * BK + lk * 8];
        #pragma unroll
        for (int j = 0; j < 4; ++j)
            bfr[j] = *(const bf16x8*)&Bs[(wc * 64 + j * 16 + lm) * BK + lk * 8];

        #pragma unroll
        for (int i = 0; i < 4; ++i)
            #pragma unroll
            for (int j = 0; j < 4; ++j)
                acc[i][j] = __builtin_amdgcn_mfma_f32_16x16x32_bf16(
                    af[i], bfr[j], acc[i][j], 0, 0, 0);
        __syncthreads();
    }

    // epilogue: C/D layout col=lane&15, row=(lane>>4)*4+reg (m89-verified)
    const long r0b = by + wr * 64 + lk * 4;
    const long c0b = bx + wc * 64 + lm;
    if (BF16OUT) {
        bf16* C = (bf16*)Cv + (long)z * sC;
        #pragma unroll
        for (int i = 0; i < 4; ++i) {
            const long rb = r0b + i * 16;
            #pragma unroll
            for (int j = 0; j < 4; ++j) {
                const long cc = c0b + j * 16;
                #pragma unroll
                for (int r = 0; r < 4; ++r)
                    C[(rb + r) * (long)ldc + cc] = (bf16)(acc[i][j][r] * scale);
            }
        }
    } else {
        float* C = (float*)Cv + (long)z * sC;
        #pragma unroll
        for (int i = 0; i < 4; ++i) {
            const long rb = r0b + i * 16;
            #pragma unroll
            for (int j = 0; j < 4; ++j) {
                const long cc = c0b + j * 16;
                #pragma unroll
                for (int r = 0; r < 4; ++r)
                    C[(rb + r) * (long)ldc + cc] = acc[i][j][r] * scale;
            }
        }
    }
}

__global__ __launch_bounds__(256) void f32_to_bf16_k(
    const float* __restrict__ in, bf16* __restrict__ out, long n)
{
    long i = ((long)blockIdx.x * blockDim.x + threadIdx.x) * 8;
    if (i + 8 > n) return;
    const float4* p = (const float4*)(in + i);
    float4 a = p[0], b = p[1];
    bf16x8 o = { (bf16)a.x, (bf16)a.y, (bf16)a.z, (bf16)a.w,
                 (bf16)b.x, (bf16)b.y, (bf16)b.z, (bf16)b.w };
    *(bf16x8*)(out + i) = o;
}

// out[c][r] = in[r][c]; in [R,C] -> out [C,R]; R,C % 32 == 0
template <typename Tin>
__global__ __launch_bounds__(256) void transpose_to_bf16(
    const Tin* __restrict__ in, bf16* __restrict__ out,
    int R, int C, long sIn, long sOut)
{
    __shared__ bf16 tile[32][33];
    in  += (long)blockIdx.z * sIn;
    out += (long)blockIdx.z * sOut;
    const int bx = blockIdx.x * 32, by = blockIdx.y * 32;
    const int tx = threadIdx.x, ty = threadIdx.y;
    #pragma unroll
    for (int r = ty; r < 32; r += 8)
        tile[r][tx] = (bf16)in[(long)(by + r) * C + bx + tx];
    __syncthreads();
    #pragma unroll
    for (int r = ty; r < 32; r += 8)
        out[(long)(bx + r) * R + by + tx] = tile[tx][r];
}

// one block per row of n=2048; in-place fp32 softmax + bf16 copy
__global__ __launch_bounds__(256) void softmax_rows(
    float* __restrict__ sc, bf16* __restrict__ wbf, int n)
{
    const long base = (long)blockIdx.x * n;
    const int t = threadIdx.x;
    const int wave = t >> 6, lane = t & 63;
    float v[8];
    #pragma unroll
    for (int k = 0; k < 8; ++k) v[k] = sc[base + t + k * 256];

    float m = v[0];
    #pragma unroll
    for (int k = 1; k < 8; ++k) m = fmaxf(m, v[k]);
    #pragma unroll
    for (int off = 32; off; off >>= 1) m = fmaxf(m, __shfl_xor(m, off, 64));
    __shared__ float red[4];
    if (lane == 0) red[wave] = m;
    __syncthreads();
    m = fmaxf(fmaxf(red[0], red[1]), fmaxf(red[2], red[3]));

    float s = 0.f;
    #pragma unroll
    for (int k = 0; k < 8; ++k) { v[k] = __expf(v[k] - m); s += v[k]; }
    #pragma unroll
    for (int off = 32; off; off >>= 1) s += __shfl_xor(s, off, 64);
    __syncthreads();
    if (lane == 0) red[wave] = s;
    __syncthreads();
    s = red[0] + red[1] + red[2] + red[3];
    const float inv = 1.0f / s;
    #pragma unroll
    for (int k = 0; k < 8; ++k) {
        float w = v[k] * inv;
        sc[base + t + k * 256]  = w;
        wbf[base + t + k * 256] = (bf16)w;
    }
}

extern "C" void kernel_launch(void* const* d_in, const int* in_sizes, int n_in,
                              void* d_out, int out_size, void* d_ws, size_t ws_size,
                              hipStream_t stream)
{
    const int Bb = 8, S = 2048, D = 1024;
    const long BSD = (long)Bb * S * D;   // 16,777,216
    const long DD  = (long)D * D;

    const float* input   = (const float*)d_in[0];
    const float* context = (const float*)d_in[1];
    const float* Wq = (const float*)d_in[2];
    const float* Wk = (const float*)d_in[3];
    const float* Wv = (const float*)d_in[4];
    const float* Wo = (const float*)d_in[5];

    // workspace layout (bf16 elements), ~176 MB with aliasing:
    bf16* Xbf = (bf16*)d_ws;        // input bf16  [16384,1024]   (later: ctx)
    bf16* Cbf = Xbf + BSD;          // context bf16               (later: Wbf lo)
    bf16* Kbf = Cbf + BSD;          // K bf16                     (later: Wbf hi)
    bf16* Qbf = Kbf + BSD;          // Q bf16
    bf16* VT  = Qbf + BSD;          // V^T bf16 [B,1024,2048]
    bf16* WqT = VT + BSD;           // weights transposed [N,K] bf16
    bf16* WkT = WqT + DD;
    bf16* WvT = WkT + DD;
    bf16* WoT = WvT + DD;
    bf16* ctxb = Xbf;               // alias: Xbf dead after Q projection
    bf16* Wbf  = Cbf;               // alias: Cbf+Kbf dead after scores; spans 2*BSD

    float* outp   = (float*)d_out;
    float* scores = outp + BSD;     // weights region used as scores scratch (in-place)

    const dim3 blk256(256);
    const dim3 tb(32, 8);

    // 1. fp32 -> bf16 converts
    f32_to_bf16_k<<<dim3((unsigned)(BSD / 8 / 256)), blk256, 0, stream>>>(input,   Xbf, BSD);
    f32_to_bf16_k<<<dim3((unsigned)(BSD / 8 / 256)), blk256, 0, stream>>>(context, Cbf, BSD);

    // 2. weight transpose+convert: [K,N] fp32 -> [N,K] bf16
    transpose_to_bf16<float><<<dim3(32, 32, 1), tb, 0, stream>>>(Wq, WqT, D, D, 0, 0);
    transpose_to_bf16<float><<<dim3(32, 32, 1), tb, 0, stream>>>(Wk, WkT, D, D, 0, 0);
    transpose_to_bf16<float><<<dim3(32, 32, 1), tb, 0, stream>>>(Wv, WvT, D, D, 0, 0);
    transpose_to_bf16<float><<<dim3(32, 32, 1), tb, 0, stream>>>(Wo, WoT, D, D, 0, 0);

    // 3. projections (batch-merged M=16384)
    gemm_bt<true><<<dim3(D / BN, (Bb * S) / BM, 1), blk256, 0, stream>>>(
        Xbf, WqT, Qbf, Bb * S, D, D, D, D, D, 0, 0, 0, 1.0f);
    gemm_bt<true><<<dim3(D / BN, (Bb * S) / BM, 1), blk256, 0, stream>>>(
        Cbf, WkT, Kbf, Bb * S, D, D, D, D, D, 0, 0, 0, 1.0f);
    // V^T directly: VT[e][s] = sum_k WvT[e][k] * Cbf[s][k]  (per batch)
    gemm_bt<true><<<dim3(S / BN, D / BM, Bb), blk256, 0, stream>>>(
        WvT, Cbf, VT, D, S, D, D, D, S, 0, (long)S * D, (long)D * S, 1.0f);

    // 4. scores = Q K^T / 32 -> fp32 into d_out weights region
    gemm_bt<false><<<dim3(S / BN, S / BM, Bb), blk256, 0, stream>>>(
        Qbf, Kbf, scores, S, S, D, D, D, S,
        (long)S * D, (long)S * D, (long)S * S, 0.03125f);

    // 5. softmax in place + bf16 copy
    softmax_rows<<<dim3(Bb * S), blk256, 0, stream>>>(scores, Wbf, S);

    // 6. ctx = W V  (A = weights bf16 [S,S], Bt = V^T [D rows, S cols])
    gemm_bt<true><<<dim3(D / BN, S / BM, Bb), blk256, 0, stream>>>(
        Wbf, VT, ctxb, S, D, S, S, S, D,
        (long)S * S, (long)D * S, (long)S * D, 1.0f);

    // 7. output = ctx Wo -> fp32 d_out
    gemm_bt<false><<<dim3(D / BN, (Bb * S) / BM, 1), blk256, 0, stream>>>(
        ctxb, WoT, outp, Bb * S, D, D, D, D, D, 0, 0, 0, 1.0f);
}

// Round 2
// 779.871 us; speedup vs baseline: 1.0569x; 1.0569x over previous
//
#include <hip/hip_runtime.h>
#include <hip/hip_bf16.h>
#include <stdint.h>

// Cross-attention: out = softmax((X Wq)(C Wk)^T / sqrt(D)) (C Wv) Wo
// Outputs: [B,S,D] fp32 output, then [B,S,S] fp32 softmax weights, concat in d_out.
// bf16 MFMA GEMMs (m97 structure) + XCD-aware 1D tile remap:
// gid%8 = XCD (MI355X round-robin dispatch); each XCD owns a contiguous
// (batch,row)-tile range with N-tiles cycling fastest -> A row-tile reused from
// the same XCD's L2 instead of being fetched by all 8 XCDs (was 8x over-fetch,
// FETCH 280MB vs 34MB ideal on projections).

typedef __bf16 bf16;
typedef __attribute__((ext_vector_type(8))) __bf16 bf16x8;
typedef __attribute__((ext_vector_type(4))) float f32x4;

#define BM 128
#define BN 128
#define BK 32

__device__ __forceinline__ void g2lds16(const void* g, void* l) {
    __builtin_amdgcn_global_load_lds(
        (__attribute__((address_space(1))) void*)g,
        (__attribute__((address_space(3))) void*)l,
        16, 0, 0);
}

// C[m][n] = scale * sum_k A[m][k] * Bt[n][k]; A:[M,K] lda, Bt:[N,K] ldb, C:[M,N] ldc.
// 1D grid; gx = N/BN tiles, gy = M/BM tiles, batches via strides sA/sB/sC.
// rowsPerXcd = (gridDim.x / gx) / 8.
template <bool BF16OUT>
__global__ __launch_bounds__(256) void gemm_bt(
    const bf16* __restrict__ A, const bf16* __restrict__ Bt, void* __restrict__ Cv,
    int K, int lda, int ldb, int ldc,
    long sA, long sB, long sC, float scale,
    int gx, int gy, int rowsPerXcd)
{
    __shared__ bf16 As[BM * BK];
    __shared__ bf16 Bs[BN * BK];

    // XCD-aware remap (assumes block i -> XCD i%8 round-robin)
    const int gid  = blockIdx.x;
    const int xcd  = gid & 7;
    const int slot = gid >> 3;
    const int tx   = slot % gx;             // N-tile (cycles fastest within XCD)
    const int row  = xcd * rowsPerXcd + slot / gx;  // combined (batch, M-tile)
    const int ty   = row % gy;
    const int z    = row / gy;

    A  += (long)z * sA;
    Bt += (long)z * sB;

    const int t    = threadIdx.x;
    const int wave = t >> 6, lane = t & 63;
    const int wr   = wave >> 1, wc = wave & 1;   // 2x2 wave grid, 64x64 each
    const int lm   = lane & 15, lk = lane >> 4;  // mfma fragment coords

    const long by = (long)ty * BM;
    const long bx = (long)tx * BN;

    f32x4 acc[4][4] = {};

    // staging: thread t loads 16B; lane-contiguous LDS (global_load_lds constraint)
    const int srow = t >> 2;            // 0..63
    const int scol = (t & 3) * 8;       // 0,8,16,24
    const bf16* Ap = A  + (by + srow) * (long)lda + scol;
    const bf16* Bp = Bt + (bx + srow) * (long)ldb + scol;
    bf16* AsW = &As[t * 8];
    bf16* BsW = &Bs[t * 8];
    const long a64 = 64L * lda, b64 = 64L * ldb;

    for (int kt = 0; kt < K; kt += BK) {
        g2lds16(Ap,       AsW);
        g2lds16(Ap + a64, AsW + 64 * BK);
        g2lds16(Bp,       BsW);
        g2lds16(Bp + b64, BsW + 64 * BK);
        Ap += BK; Bp += BK;
        __builtin_amdgcn_s_waitcnt(0x0f70);   // vmcnt(0)
        __syncthreads();

        bf16x8 af[4], bfr[4];
        #pragma unroll
        for (int i = 0; i < 4; ++i)
            af[i] = *(const bf16x8*)&As[(wr * 64 + i * 16 + lm) * BK + lk * 8];
        #pragma unroll
        for (int j = 0; j < 4; ++j)
            bfr[j] = *(const bf16x8*)&Bs[(wc * 64 + j * 16 + lm) * BK + lk * 8];

        #pragma unroll
        for (int i = 0; i < 4; ++i)
            #pragma unroll
            for (int j = 0; j < 4; ++j)
                acc[i][j] = __builtin_amdgcn_mfma_f32_16x16x32_bf16(
                    af[i], bfr[j], acc[i][j], 0, 0, 0);
        __syncthreads();
    }

    // epilogue: C/D layout col=lane&15, row=(lane>>4)*4+reg (m89-verified)
    const long r0b = by + wr * 64 + lk * 4;
    const long c0b = bx + wc * 64 + lm;
    if (BF16OUT) {
        bf16* C = (bf16*)Cv + (long)z * sC;
        #pragma unroll
        for (int i = 0; i < 4; ++i) {
            const long rb = r0b + i * 16;
            #pragma unroll
            for (int j = 0; j < 4; ++j) {
                const long cc = c0b + j * 16;
                #pragma unroll
                for (int r = 0; r < 4; ++r)
                    C[(rb + r) * (long)ldc + cc] = (bf16)(acc[i][j][r] * scale);
            }
        }
    } else {
        float* C = (float*)Cv + (long)z * sC;
        #pragma unroll
        for (int i = 0; i < 4; ++i) {
            const long rb = r0b + i * 16;
            #pragma unroll
            for (int j = 0; j < 4; ++j) {
                const long cc = c0b + j * 16;
                #pragma unroll
                for (int r = 0; r < 4; ++r)
                    C[(rb + r) * (long)ldc + cc] = acc[i][j][r] * scale;
            }
        }
    }
}

__global__ __launch_bounds__(256) void f32_to_bf16_k(
    const float* __restrict__ in, bf16* __restrict__ out, long n)
{
    long i = ((long)blockIdx.x * blockDim.x + threadIdx.x) * 8;
    if (i + 8 > n) return;
    const float4* p = (const float4*)(in + i);
    float4 a = p[0], b = p[1];
    bf16x8 o = { (bf16)a.x, (bf16)a.y, (bf16)a.z, (bf16)a.w,
                 (bf16)b.x, (bf16)b.y, (bf16)b.z, (bf16)b.w };
    *(bf16x8*)(out + i) = o;
}

// out[c][r] = in[r][c]; in [R,C] -> out [C,R]; R,C % 32 == 0
template <typename Tin>
__global__ __launch_bounds__(256) void transpose_to_bf16(
    const Tin* __restrict__ in, bf16* __restrict__ out,
    int R, int C, long sIn, long sOut)
{
    __shared__ bf16 tile[32][33];
    in  += (long)blockIdx.z * sIn;
    out += (long)blockIdx.z * sOut;
    const int bx = blockIdx.x * 32, by = blockIdx.y * 32;
    const int tx = threadIdx.x, ty = threadIdx.y;
    #pragma unroll
    for (int r = ty; r < 32; r += 8)
        tile[r][tx] = (bf16)in[(long)(by + r) * C + bx + tx];
    __syncthreads();
    #pragma unroll
    for (int r = ty; r < 32; r += 8)
        out[(long)(bx + r) * R + by + tx] = tile[tx][r];
}

// one block per row of n=2048; in-place fp32 softmax + bf16 copy
__global__ __launch_bounds__(256) void softmax_rows(
    float* __restrict__ sc, bf16* __restrict__ wbf, int n)
{
    const long base = (long)blockIdx.x * n;
    const int t = threadIdx.x;
    const int wave = t >> 6, lane = t & 63;
    float v[8];
    #pragma unroll
    for (int k = 0; k < 8; ++k) v[k] = sc[base + t + k * 256];

    float m = v[0];
    #pragma unroll
    for (int k = 1; k < 8; ++k) m = fmaxf(m, v[k]);
    #pragma unroll
    for (int off = 32; off; off >>= 1) m = fmaxf(m, __shfl_xor(m, off, 64));
    __shared__ float red[4];
    if (lane == 0) red[wave] = m;
    __syncthreads();
    m = fmaxf(fmaxf(red[0], red[1]), fmaxf(red[2], red[3]));

    float s = 0.f;
    #pragma unroll
    for (int k = 0; k < 8; ++k) { v[k] = __expf(v[k] - m); s += v[k]; }
    #pragma unroll
    for (int off = 32; off; off >>= 1) s += __shfl_xor(s, off, 64);
    __syncthreads();
    if (lane == 0) red[wave] = s;
    __syncthreads();
    s = red[0] + red[1] + red[2] + red[3];
    const float inv = 1.0f / s;
    #pragma unroll
    for (int k = 0; k < 8; ++k) {
        float w = v[k] * inv;
        sc[base + t + k * 256]  = w;
        wbf[base + t + k * 256] = (bf16)w;
    }
}

extern "C" void kernel_launch(void* const* d_in, const int* in_sizes, int n_in,
                              void* d_out, int out_size, void* d_ws, size_t ws_size,
                              hipStream_t stream)
{
    const int Bb = 8, S = 2048, D = 1024;
    const long BSD = (long)Bb * S * D;   // 16,777,216
    const long DD  = (long)D * D;

    const float* input   = (const float*)d_in[0];
    const float* context = (const float*)d_in[1];
    const float* Wq = (const float*)d_in[2];
    const float* Wk = (const float*)d_in[3];
    const float* Wv = (const float*)d_in[4];
    const float* Wo = (const float*)d_in[5];

    // workspace layout (bf16 elements), ~176 MB with aliasing:
    bf16* Xbf = (bf16*)d_ws;        // input bf16  [16384,1024]   (later: ctx)
    bf16* Cbf = Xbf + BSD;          // context bf16               (later: Wbf lo)
    bf16* Kbf = Cbf + BSD;          // K bf16                     (later: Wbf hi)
    bf16* Qbf = Kbf + BSD;          // Q bf16
    bf16* VT  = Qbf + BSD;          // V^T bf16 [B,1024,2048]
    bf16* WqT = VT + BSD;           // weights transposed [N,K] bf16
    bf16* WkT = WqT + DD;
    bf16* WvT = WkT + DD;
    bf16* WoT = WvT + DD;
    bf16* ctxb = Xbf;               // alias: Xbf dead after Q projection
    bf16* Wbf  = Cbf;               // alias: Cbf+Kbf dead after scores; spans 2*BSD

    float* outp   = (float*)d_out;
    float* scores = outp + BSD;     // weights region used as scores scratch (in-place)

    const dim3 blk256(256);
    const dim3 tb(32, 8);

    // 1. fp32 -> bf16 converts
    f32_to_bf16_k<<<dim3((unsigned)(BSD / 8 / 256)), blk256, 0, stream>>>(input,   Xbf, BSD);
    f32_to_bf16_k<<<dim3((unsigned)(BSD / 8 / 256)), blk256, 0, stream>>>(context, Cbf, BSD);

    // 2. weight transpose+convert: [K,N] fp32 -> [N,K] bf16
    transpose_to_bf16<float><<<dim3(32, 32, 1), tb, 0, stream>>>(Wq, WqT, D, D, 0, 0);
    transpose_to_bf16<float><<<dim3(32, 32, 1), tb, 0, stream>>>(Wk, WkT, D, D, 0, 0);
    transpose_to_bf16<float><<<dim3(32, 32, 1), tb, 0, stream>>>(Wv, WvT, D, D, 0, 0);
    transpose_to_bf16<float><<<dim3(32, 32, 1), tb, 0, stream>>>(Wo, WoT, D, D, 0, 0);

    // 3. projections (batch-merged M=16384): gx=8, gy=128, total=1024, rpx=16
    gemm_bt<true><<<dim3(1024), blk256, 0, stream>>>(
        Xbf, WqT, Qbf, D, D, D, D, 0, 0, 0, 1.0f, 8, 128, 16);
    gemm_bt<true><<<dim3(1024), blk256, 0, stream>>>(
        Cbf, WkT, Kbf, D, D, D, D, 0, 0, 0, 1.0f, 8, 128, 16);
    // V^T directly: VT[e][s] = sum_k WvT[e][k] * Cbf[s][k]; gx=16, gy=8, z=8 -> rpx=8
    gemm_bt<true><<<dim3(1024), blk256, 0, stream>>>(
        WvT, Cbf, VT, D, D, D, S, 0, (long)S * D, (long)D * S, 1.0f, 16, 8, 8);

    // 4. scores = Q K^T / 32 -> fp32; gx=16, gy=16, z=8, total=2048, rpx=16
    gemm_bt<false><<<dim3(2048), blk256, 0, stream>>>(
        Qbf, Kbf, scores, D, D, D, S,
        (long)S * D, (long)S * D, (long)S * S, 0.03125f, 16, 16, 16);

    // 5. softmax in place + bf16 copy
    softmax_rows<<<dim3(Bb * S), blk256, 0, stream>>>(scores, Wbf, S);

    // 6. ctx = W V; gx=8, gy=16, z=8, total=1024, rpx=16
    gemm_bt<true><<<dim3(1024), blk256, 0, stream>>>(
        Wbf, VT, ctxb, S, S, S, D,
        (long)S * S, (long)D * S, (long)S * D, 1.0f, 8, 16, 16);

    // 7. output = ctx Wo -> fp32 d_out; gx=8, gy=128, rpx=16
    gemm_bt<false><<<dim3(1024), blk256, 0, stream>>>(
        ctxb, WoT, outp, D, D, D, D, 0, 0, 0, 1.0f, 8, 128, 16);
}